// Round 1
// baseline (12700.614 us; speedup 1.0000x reference)
//
#include <hip/hip_runtime.h>

#define NUM_USERS 100000
#define NUM_ITEMS 50000
#define NUM_OTHERS 20000
#define N_NODES 170000   // NUM_USERS + NUM_ITEMS + NUM_OTHERS
#define DIM 64
#define NNZ 5000000
#define BATCH 8192

// ---------------------------------------------------------------------------
// Kernel 1: cur0 = concat(user_emb, item_emb, other_emb)   (float4 granularity)
// ---------------------------------------------------------------------------
__global__ void build_cur0(const float* __restrict__ ue,
                           const float* __restrict__ ie,
                           const float* __restrict__ oe,
                           float4* __restrict__ cur) {
    const int total = N_NODES * (DIM / 4);   // 2,720,000 float4
    for (int i = blockIdx.x * blockDim.x + threadIdx.x; i < total;
         i += gridDim.x * blockDim.x) {
        const int node = i >> 4;       // / 16
        const int sub  = i & 15;
        const float* src;
        if (node < NUM_USERS)                 src = ue + (size_t)node * DIM;
        else if (node < NUM_USERS + NUM_ITEMS) src = ie + (size_t)(node - NUM_USERS) * DIM;
        else                                   src = oe + (size_t)(node - NUM_USERS - NUM_ITEMS) * DIM;
        cur[i] = reinterpret_cast<const float4*>(src)[sub];
    }
}

// ---------------------------------------------------------------------------
// Kernel 2: init batch accumulators with layer-0 embeddings
//   uacc[b] = user_emb[users[b]],  iacc[b] = item_emb[items[b]]
// ---------------------------------------------------------------------------
__global__ void init_acc(const int* __restrict__ users,
                         const int* __restrict__ items,
                         const float* __restrict__ ue,
                         const float* __restrict__ ie,
                         float4* __restrict__ uacc,
                         float4* __restrict__ iacc) {
    const int total = BATCH * (DIM / 4);
    int i = blockIdx.x * blockDim.x + threadIdx.x;
    if (i >= total) return;
    const int b = i >> 4;
    const int sub = i & 15;
    uacc[i] = reinterpret_cast<const float4*>(ue + (size_t)users[b] * DIM)[sub];
    iacc[i] = reinterpret_cast<const float4*>(ie + (size_t)items[b] * DIM)[sub];
}

// ---------------------------------------------------------------------------
// Kernel 3: SpMM scatter:  y[row[e]] += vals[e] * x[col[e]]
//   16 threads per nnz, each handles one float4 chunk (4 atomicAdds).
// ---------------------------------------------------------------------------
__global__ void spmm_atomic(const float* __restrict__ vals,
                            const int* __restrict__ rows,
                            const int* __restrict__ cols,
                            const float* __restrict__ x,
                            float* __restrict__ y) {
    const int total = NNZ * 16;   // 80M, fits in int
    for (int i = blockIdx.x * blockDim.x + threadIdx.x; i < total;
         i += gridDim.x * blockDim.x) {
        const int e   = i >> 4;
        const int sub = i & 15;
        const float v = vals[e];
        const int   r = rows[e];
        const int   c = cols[e];
        const float4 xv = reinterpret_cast<const float4*>(x + (size_t)c * DIM)[sub];
        float* yp = y + (size_t)r * DIM + sub * 4;
        atomicAdd(yp + 0, v * xv.x);
        atomicAdd(yp + 1, v * xv.y);
        atomicAdd(yp + 2, v * xv.z);
        atomicAdd(yp + 3, v * xv.w);
    }
}

// ---------------------------------------------------------------------------
// Kernel 4: add this layer's output at the batch rows into the accumulators
// ---------------------------------------------------------------------------
__global__ void gather_add(const int* __restrict__ users,
                           const int* __restrict__ items,
                           const float4* __restrict__ y,
                           float4* __restrict__ uacc,
                           float4* __restrict__ iacc) {
    const int total = BATCH * (DIM / 4);
    int i = blockIdx.x * blockDim.x + threadIdx.x;
    if (i >= total) return;
    const int b = i >> 4;
    const int sub = i & 15;
    const int un = users[b];
    const int in = NUM_USERS + items[b];
    float4 a = uacc[i];
    const float4 yu = y[un * (DIM / 4) + sub];
    a.x += yu.x; a.y += yu.y; a.z += yu.z; a.w += yu.w;
    uacc[i] = a;
    float4 bacc = iacc[i];
    const float4 yi = y[in * (DIM / 4) + sub];
    bacc.x += yi.x; bacc.y += yi.y; bacc.z += yi.z; bacc.w += yi.w;
    iacc[i] = bacc;
}

// ---------------------------------------------------------------------------
// Kernel 5: gamma[b] = dot(uacc[b], iacc[b]) / 16   ((acc/4)·(acc/4))
//   one wave (64 lanes) per batch element
// ---------------------------------------------------------------------------
__global__ void dot_out(const float* __restrict__ uacc,
                        const float* __restrict__ iacc,
                        float* __restrict__ gamma) {
    const int b = blockIdx.x * (blockDim.x / 64) + (threadIdx.x / 64);
    const int lane = threadIdx.x & 63;
    if (b >= BATCH) return;
    float p = uacc[b * DIM + lane] * iacc[b * DIM + lane];
    #pragma unroll
    for (int off = 32; off > 0; off >>= 1) p += __shfl_down(p, off);
    if (lane == 0) gamma[b] = p * 0.0625f;   // 1/16
}

// ---------------------------------------------------------------------------
extern "C" void kernel_launch(void* const* d_in, const int* in_sizes, int n_in,
                              void* d_out, int out_size, void* d_ws, size_t ws_size,
                              hipStream_t stream) {
    const float* ue    = (const float*)d_in[0];
    const float* ie    = (const float*)d_in[1];
    const float* oe    = (const float*)d_in[2];
    const float* vals  = (const float*)d_in[3];
    const int*   rows  = (const int*)d_in[4];
    const int*   cols  = (const int*)d_in[5];
    const int*   users = (const int*)d_in[6];
    const int*   items = (const int*)d_in[7];
    float* out = (float*)d_out;

    // workspace layout
    float* cur  = (float*)d_ws;                       // N_NODES*64 floats
    float* nxt  = cur  + (size_t)N_NODES * DIM;       // N_NODES*64 floats
    float* uacc = nxt  + (size_t)N_NODES * DIM;       // BATCH*64
    float* iacc = uacc + (size_t)BATCH * DIM;         // BATCH*64

    build_cur0<<<2048, 256, 0, stream>>>(ue, ie, oe, (float4*)cur);
    init_acc<<<(BATCH * 16 + 255) / 256, 256, 0, stream>>>(users, items, ue, ie,
                                                           (float4*)uacc, (float4*)iacc);

    for (int layer = 0; layer < 3; ++layer) {
        hipMemsetAsync(nxt, 0, (size_t)N_NODES * DIM * sizeof(float), stream);
        spmm_atomic<<<4096, 256, 0, stream>>>(vals, rows, cols, cur, nxt);
        gather_add<<<(BATCH * 16 + 255) / 256, 256, 0, stream>>>(users, items,
                                                                 (const float4*)nxt,
                                                                 (float4*)uacc, (float4*)iacc);
        float* t = cur; cur = nxt; nxt = t;
    }

    dot_out<<<BATCH / 4, 256, 0, stream>>>(uacc, iacc, out);
}

// Round 2
// 1039.984 us; speedup vs baseline: 12.2123x; 12.2123x over previous
//
#include <hip/hip_runtime.h>

#define NUM_USERS 100000
#define NUM_ITEMS 50000
#define NUM_OTHERS 20000
#define N_NODES 170000   // NUM_USERS + NUM_ITEMS + NUM_OTHERS
#define DIM 64
#define NNZ 5000000
#define BATCH 8192

#define SCAN_BS 256
#define NB ((N_NODES + SCAN_BS - 1) / SCAN_BS)   // 665

// ---------------------------------------------------------------------------
// cur0 = concat(user_emb, item_emb, other_emb)
// ---------------------------------------------------------------------------
__global__ void build_cur0(const float* __restrict__ ue,
                           const float* __restrict__ ie,
                           const float* __restrict__ oe,
                           float4* __restrict__ cur) {
    const int total = N_NODES * (DIM / 4);
    for (int i = blockIdx.x * blockDim.x + threadIdx.x; i < total;
         i += gridDim.x * blockDim.x) {
        const int node = i >> 4;
        const int sub  = i & 15;
        const float* src;
        if (node < NUM_USERS)                  src = ue + (size_t)node * DIM;
        else if (node < NUM_USERS + NUM_ITEMS) src = ie + (size_t)(node - NUM_USERS) * DIM;
        else                                   src = oe + (size_t)(node - NUM_USERS - NUM_ITEMS) * DIM;
        cur[i] = reinterpret_cast<const float4*>(src)[sub];
    }
}

// ---------------------------------------------------------------------------
// batch accumulators start as layer-0 embeddings
// ---------------------------------------------------------------------------
__global__ void init_acc(const int* __restrict__ users,
                         const int* __restrict__ items,
                         const float* __restrict__ ue,
                         const float* __restrict__ ie,
                         float4* __restrict__ uacc,
                         float4* __restrict__ iacc) {
    const int total = BATCH * (DIM / 4);
    int i = blockIdx.x * blockDim.x + threadIdx.x;
    if (i >= total) return;
    const int b = i >> 4;
    const int sub = i & 15;
    uacc[i] = reinterpret_cast<const float4*>(ue + (size_t)users[b] * DIM)[sub];
    iacc[i] = reinterpret_cast<const float4*>(ie + (size_t)items[b] * DIM)[sub];
}

// ---------------------------------------------------------------------------
// CSR build: histogram -> 3-phase exclusive scan -> scatter (col,val) pairs
// ---------------------------------------------------------------------------
__global__ void hist_rows(const int* __restrict__ rows, int* __restrict__ count) {
    for (int e = blockIdx.x * blockDim.x + threadIdx.x; e < NNZ;
         e += gridDim.x * blockDim.x) {
        atomicAdd(&count[rows[e]], 1);
    }
}

__global__ void scan_partial(const int* __restrict__ count,
                             int* __restrict__ row_start,
                             int* __restrict__ blockSums) {
    __shared__ int lds[SCAN_BS];
    const int t = threadIdx.x;
    const int i = blockIdx.x * SCAN_BS + t;
    const int v = (i < N_NODES) ? count[i] : 0;
    lds[t] = v;
    __syncthreads();
    int acc = v;
    for (int off = 1; off < SCAN_BS; off <<= 1) {
        const int add = (t >= off) ? lds[t - off] : 0;
        __syncthreads();
        acc += add;
        lds[t] = acc;
        __syncthreads();
    }
    if (i < N_NODES) row_start[i] = acc - v;          // exclusive within block
    if (t == SCAN_BS - 1) blockSums[blockIdx.x] = acc; // block total
}

__global__ void scan_sums(int* __restrict__ blockSums) {
    __shared__ int lds[1024];
    const int t = threadIdx.x;
    const int v = (t < NB) ? blockSums[t] : 0;
    lds[t] = v;
    __syncthreads();
    int acc = v;
    for (int off = 1; off < 1024; off <<= 1) {
        const int add = (t >= off) ? lds[t - off] : 0;
        __syncthreads();
        acc += add;
        lds[t] = acc;
        __syncthreads();
    }
    if (t < NB) blockSums[t] = acc - v;                // exclusive
}

__global__ void scan_add(int* __restrict__ row_start,
                         const int* __restrict__ blockSums,
                         int* __restrict__ cursor) {
    const int i = blockIdx.x * SCAN_BS + threadIdx.x;
    if (i < N_NODES) {
        const int v = row_start[i] + blockSums[blockIdx.x];
        row_start[i] = v;
        cursor[i] = v;
    }
    if (i == 0) row_start[N_NODES] = NNZ;
}

__global__ void scatter_edges(const float* __restrict__ vals,
                              const int* __restrict__ rows,
                              const int* __restrict__ cols,
                              int* __restrict__ cursor,
                              int2* __restrict__ packed) {
    for (int e = blockIdx.x * blockDim.x + threadIdx.x; e < NNZ;
         e += gridDim.x * blockDim.x) {
        const int r = rows[e];
        const int p = atomicAdd(&cursor[r], 1);
        int2 pk;
        pk.x = cols[e];
        pk.y = __float_as_int(vals[e]);
        packed[p] = pk;
    }
}

// ---------------------------------------------------------------------------
// SpMM, gather-form: one wave per row, lane = dim element. No atomics.
// ---------------------------------------------------------------------------
__global__ __launch_bounds__(256) void spmm_csr(const int* __restrict__ row_start,
                                                const int2* __restrict__ packed,
                                                const float* __restrict__ x,
                                                float* __restrict__ y) {
    const int row  = blockIdx.x * 4 + (threadIdx.x >> 6);
    const int lane = threadIdx.x & 63;
    if (row >= N_NODES) return;
    const int s = row_start[row];
    const int e = row_start[row + 1];
    float acc = 0.f;
    int i = s;
    for (; i + 4 <= e; i += 4) {
        const int2 p0 = packed[i + 0];
        const int2 p1 = packed[i + 1];
        const int2 p2 = packed[i + 2];
        const int2 p3 = packed[i + 3];
        const float x0 = x[(size_t)p0.x * DIM + lane];
        const float x1 = x[(size_t)p1.x * DIM + lane];
        const float x2 = x[(size_t)p2.x * DIM + lane];
        const float x3 = x[(size_t)p3.x * DIM + lane];
        acc = fmaf(__int_as_float(p0.y), x0, acc);
        acc = fmaf(__int_as_float(p1.y), x1, acc);
        acc = fmaf(__int_as_float(p2.y), x2, acc);
        acc = fmaf(__int_as_float(p3.y), x3, acc);
    }
    for (; i < e; ++i) {
        const int2 p = packed[i];
        acc = fmaf(__int_as_float(p.y), x[(size_t)p.x * DIM + lane], acc);
    }
    y[(size_t)row * DIM + lane] = acc;
}

// ---------------------------------------------------------------------------
// Layer-3: only the batch rows are ever read, so compute just those and
// accumulate directly into uacc/iacc. One wave per (batch, user|item).
// ---------------------------------------------------------------------------
__global__ __launch_bounds__(256) void spmm_batch_final(const int* __restrict__ row_start,
                                                        const int2* __restrict__ packed,
                                                        const float* __restrict__ x,
                                                        const int* __restrict__ users,
                                                        const int* __restrict__ items,
                                                        float* __restrict__ uacc,
                                                        float* __restrict__ iacc) {
    const int w    = blockIdx.x * 4 + (threadIdx.x >> 6);   // [0, 2*BATCH)
    const int lane = threadIdx.x & 63;
    if (w >= 2 * BATCH) return;
    const int b = w >> 1;
    const int isItem = w & 1;
    const int row = isItem ? (NUM_USERS + items[b]) : users[b];
    const int s = row_start[row];
    const int e = row_start[row + 1];
    float acc = 0.f;
    int i = s;
    for (; i + 4 <= e; i += 4) {
        const int2 p0 = packed[i + 0];
        const int2 p1 = packed[i + 1];
        const int2 p2 = packed[i + 2];
        const int2 p3 = packed[i + 3];
        const float x0 = x[(size_t)p0.x * DIM + lane];
        const float x1 = x[(size_t)p1.x * DIM + lane];
        const float x2 = x[(size_t)p2.x * DIM + lane];
        const float x3 = x[(size_t)p3.x * DIM + lane];
        acc = fmaf(__int_as_float(p0.y), x0, acc);
        acc = fmaf(__int_as_float(p1.y), x1, acc);
        acc = fmaf(__int_as_float(p2.y), x2, acc);
        acc = fmaf(__int_as_float(p3.y), x3, acc);
    }
    for (; i < e; ++i) {
        const int2 p = packed[i];
        acc = fmaf(__int_as_float(p.y), x[(size_t)p.x * DIM + lane], acc);
    }
    float* dst = isItem ? iacc : uacc;
    dst[(size_t)b * DIM + lane] += acc;
}

// ---------------------------------------------------------------------------
// uacc/iacc += y at the batch rows (layers 1 and 2)
// ---------------------------------------------------------------------------
__global__ void gather_add(const int* __restrict__ users,
                           const int* __restrict__ items,
                           const float4* __restrict__ y,
                           float4* __restrict__ uacc,
                           float4* __restrict__ iacc) {
    const int total = BATCH * (DIM / 4);
    int i = blockIdx.x * blockDim.x + threadIdx.x;
    if (i >= total) return;
    const int b = i >> 4;
    const int sub = i & 15;
    const int un = users[b];
    const int in = NUM_USERS + items[b];
    float4 a = uacc[i];
    const float4 yu = y[un * (DIM / 4) + sub];
    a.x += yu.x; a.y += yu.y; a.z += yu.z; a.w += yu.w;
    uacc[i] = a;
    float4 c = iacc[i];
    const float4 yi = y[in * (DIM / 4) + sub];
    c.x += yi.x; c.y += yi.y; c.z += yi.z; c.w += yi.w;
    iacc[i] = c;
}

// ---------------------------------------------------------------------------
// gamma[b] = dot(uacc[b], iacc[b]) / 16     ((acc/4)·(acc/4))
// ---------------------------------------------------------------------------
__global__ void dot_out(const float* __restrict__ uacc,
                        const float* __restrict__ iacc,
                        float* __restrict__ gamma) {
    const int b = blockIdx.x * (blockDim.x / 64) + (threadIdx.x / 64);
    const int lane = threadIdx.x & 63;
    if (b >= BATCH) return;
    float p = uacc[b * DIM + lane] * iacc[b * DIM + lane];
    #pragma unroll
    for (int off = 32; off > 0; off >>= 1) p += __shfl_down(p, off);
    if (lane == 0) gamma[b] = p * 0.0625f;
}

// ---------------------------------------------------------------------------
extern "C" void kernel_launch(void* const* d_in, const int* in_sizes, int n_in,
                              void* d_out, int out_size, void* d_ws, size_t ws_size,
                              hipStream_t stream) {
    const float* ue    = (const float*)d_in[0];
    const float* ie    = (const float*)d_in[1];
    const float* oe    = (const float*)d_in[2];
    const float* vals  = (const float*)d_in[3];
    const int*   rows  = (const int*)d_in[4];
    const int*   cols  = (const int*)d_in[5];
    const int*   users = (const int*)d_in[6];
    const int*   items = (const int*)d_in[7];
    float* out = (float*)d_out;

    // ---- workspace layout (all 16B aligned) ----
    char* p = (char*)d_ws;
    float* cur  = (float*)p;            p += (size_t)N_NODES * DIM * sizeof(float);   // 43.52 MB
    float* nxt  = (float*)p;            p += (size_t)N_NODES * DIM * sizeof(float);   // 43.52 MB
    float* uacc = (float*)p;            p += (size_t)BATCH * DIM * sizeof(float);     //  2.10 MB
    float* iacc = (float*)p;            p += (size_t)BATCH * DIM * sizeof(float);     //  2.10 MB
    int2*  packed    = (int2*)p;        p += (size_t)NNZ * sizeof(int2);              // 40.00 MB
    int*   row_start = (int*)p;         p += (size_t)(N_NODES + 4) * sizeof(int);     //  0.68 MB
    int*   cursor    = (int*)p;         p += (size_t)N_NODES * sizeof(int);           //  0.68 MB  (also the histogram)
    int*   blockSums = (int*)p;         p += 1024 * sizeof(int);

    // ---- node matrix + batch accumulator init ----
    build_cur0<<<2048, 256, 0, stream>>>(ue, ie, oe, (float4*)cur);
    init_acc<<<(BATCH * 16 + 255) / 256, 256, 0, stream>>>(users, items, ue, ie,
                                                           (float4*)uacc, (float4*)iacc);

    // ---- CSR build ----
    hipMemsetAsync(cursor, 0, (size_t)N_NODES * sizeof(int), stream);
    hist_rows<<<2048, 256, 0, stream>>>(rows, cursor);
    scan_partial<<<NB, SCAN_BS, 0, stream>>>(cursor, row_start, blockSums);
    scan_sums<<<1, 1024, 0, stream>>>(blockSums);
    scan_add<<<NB, SCAN_BS, 0, stream>>>(row_start, blockSums, cursor);
    scatter_edges<<<2048, 256, 0, stream>>>(vals, rows, cols, cursor, packed);

    // ---- layers 1 and 2: full SpMM, accumulate batch rows ----
    for (int layer = 0; layer < 2; ++layer) {
        spmm_csr<<<(N_NODES + 3) / 4, 256, 0, stream>>>(row_start, packed, cur, nxt);
        gather_add<<<(BATCH * 16 + 255) / 256, 256, 0, stream>>>(users, items,
                                                                 (const float4*)nxt,
                                                                 (float4*)uacc, (float4*)iacc);
        float* t = cur; cur = nxt; nxt = t;
    }

    // ---- layer 3: only the batch rows ----
    spmm_batch_final<<<(2 * BATCH + 3) / 4, 256, 0, stream>>>(row_start, packed, cur,
                                                              users, items, uacc, iacc);

    // ---- output ----
    dot_out<<<BATCH / 4, 256, 0, stream>>>(uacc, iacc, out);
}

// Round 3
// 650.537 us; speedup vs baseline: 19.5233x; 1.5987x over previous
//
#include <hip/hip_runtime.h>

#define NUM_USERS 100000
#define NUM_ITEMS 50000
#define NUM_OTHERS 20000
#define N_NODES 170000   // NUM_USERS + NUM_ITEMS + NUM_OTHERS
#define DIM 64
#define NNZ 5000000
#define BATCH 8192

#define BSHIFT 9
#define RPB (1 << BSHIFT)                       // 512 rows per bucket
#define NBUCK ((N_NODES + RPB - 1) / RPB)       // 333 buckets
#define NBLK 512                                // blocks for hist/scatter passes
#define CHUNK ((NNZ + NBLK - 1) / NBLK)         // 9766 edges per block

// ---------------------------------------------------------------------------
// cur0 = concat(user_emb, item_emb, other_emb)
// ---------------------------------------------------------------------------
__global__ void build_cur0(const float* __restrict__ ue,
                           const float* __restrict__ ie,
                           const float* __restrict__ oe,
                           float4* __restrict__ cur) {
    const int total = N_NODES * (DIM / 4);
    for (int i = blockIdx.x * blockDim.x + threadIdx.x; i < total;
         i += gridDim.x * blockDim.x) {
        const int node = i >> 4;
        const int sub  = i & 15;
        const float* src;
        if (node < NUM_USERS)                  src = ue + (size_t)node * DIM;
        else if (node < NUM_USERS + NUM_ITEMS) src = ie + (size_t)(node - NUM_USERS) * DIM;
        else                                   src = oe + (size_t)(node - NUM_USERS - NUM_ITEMS) * DIM;
        cur[i] = reinterpret_cast<const float4*>(src)[sub];
    }
}

// ---------------------------------------------------------------------------
// batch accumulators start as layer-0 embeddings
// ---------------------------------------------------------------------------
__global__ void init_acc(const int* __restrict__ users,
                         const int* __restrict__ items,
                         const float* __restrict__ ue,
                         const float* __restrict__ ie,
                         float4* __restrict__ uacc,
                         float4* __restrict__ iacc) {
    const int total = BATCH * (DIM / 4);
    int i = blockIdx.x * blockDim.x + threadIdx.x;
    if (i >= total) return;
    const int b = i >> 4;
    const int sub = i & 15;
    uacc[i] = reinterpret_cast<const float4*>(ue + (size_t)users[b] * DIM)[sub];
    iacc[i] = reinterpret_cast<const float4*>(ie + (size_t)items[b] * DIM)[sub];
}

// ---------------------------------------------------------------------------
// Pass 1: bucket histogram (per-block LDS pre-aggregation -> 340K global atomics)
// ---------------------------------------------------------------------------
__global__ __launch_bounds__(256) void bucket_hist(const int* __restrict__ rows,
                                                   int* __restrict__ bucket_cnt) {
    __shared__ int h[NBUCK];
    for (int i = threadIdx.x; i < NBUCK; i += 256) h[i] = 0;
    __syncthreads();
    const int s = blockIdx.x * CHUNK;
    const int e = min(s + CHUNK, NNZ);
    for (int i = s + threadIdx.x; i < e; i += 256)
        atomicAdd(&h[rows[i] >> BSHIFT], 1);
    __syncthreads();
    for (int i = threadIdx.x; i < NBUCK; i += 256)
        if (h[i]) atomicAdd(&bucket_cnt[i], h[i]);
}

// ---------------------------------------------------------------------------
// Pass 2: exclusive scan of 333 bucket counts (one block)
// ---------------------------------------------------------------------------
__global__ __launch_bounds__(512) void bucket_scan(const int* __restrict__ bucket_cnt,
                                                   int* __restrict__ bucket_base,
                                                   int* __restrict__ gcursor) {
    __shared__ int lds[512];
    const int t = threadIdx.x;
    const int v = (t < NBUCK) ? bucket_cnt[t] : 0;
    lds[t] = v;
    __syncthreads();
    int acc = v;
    for (int off = 1; off < 512; off <<= 1) {
        const int add = (t >= off) ? lds[t - off] : 0;
        __syncthreads();
        acc += add;
        lds[t] = acc;
        __syncthreads();
    }
    if (t < NBUCK) {
        const int ex = acc - v;
        bucket_base[t] = ex;
        gcursor[t] = ex;
    }
    if (t == 0) bucket_base[NBUCK] = NNZ;
}

// ---------------------------------------------------------------------------
// Pass 3: scatter edges into bucket-major order. Per-block: LDS histogram,
// reserve contiguous ranges per bucket (1 global atomic per touched bucket),
// then append sequentially into the reserved ranges.
// ---------------------------------------------------------------------------
__global__ __launch_bounds__(256) void bucket_scatter(const int* __restrict__ rows,
                                                      const int* __restrict__ cols,
                                                      const float* __restrict__ vals,
                                                      int* __restrict__ gcursor,
                                                      int2* __restrict__ brc,
                                                      float* __restrict__ bv) {
    __shared__ int h[NBUCK];
    __shared__ int base[NBUCK];
    for (int i = threadIdx.x; i < NBUCK; i += 256) h[i] = 0;
    __syncthreads();
    const int s = blockIdx.x * CHUNK;
    const int e = min(s + CHUNK, NNZ);
    for (int i = s + threadIdx.x; i < e; i += 256)
        atomicAdd(&h[rows[i] >> BSHIFT], 1);
    __syncthreads();
    for (int i = threadIdx.x; i < NBUCK; i += 256)
        base[i] = h[i] ? atomicAdd(&gcursor[i], h[i]) : 0;
    __syncthreads();
    for (int i = threadIdx.x; i < NBUCK; i += 256) h[i] = 0;
    __syncthreads();
    for (int i = s + threadIdx.x; i < e; i += 256) {
        const int r  = rows[i];
        const int bk = r >> BSHIFT;
        const int pos = base[bk] + atomicAdd(&h[bk], 1);
        brc[pos] = make_int2(r, cols[i]);
        bv[pos]  = vals[i];
    }
}

// ---------------------------------------------------------------------------
// Pass 4: per-bucket counting sort -> final CSR (packed (col,val)) + row_start.
// One block per bucket; bucket CSR region ~120KB (L2-resident scatter).
// ---------------------------------------------------------------------------
__global__ __launch_bounds__(512) void bucket_to_csr(const int* __restrict__ bucket_base,
                                                     const int2* __restrict__ brc,
                                                     const float* __restrict__ bv,
                                                     int* __restrict__ row_start,
                                                     int2* __restrict__ packed) {
    __shared__ int cnt[RPB];
    __shared__ int rs[RPB];
    const int k = blockIdx.x;
    const int rbase = k << BSHIFT;
    const int bs = bucket_base[k];
    const int be = bucket_base[k + 1];
    const int t = threadIdx.x;

    cnt[t] = 0;
    __syncthreads();
    for (int i = bs + t; i < be; i += 512)
        atomicAdd(&cnt[brc[i].x - rbase], 1);
    __syncthreads();

    // exclusive scan of 512 counts (Hillis-Steele)
    const int v = cnt[t];
    int acc = v;
    rs[t] = v;
    __syncthreads();
    for (int off = 1; off < 512; off <<= 1) {
        const int add = (t >= off) ? rs[t - off] : 0;
        __syncthreads();
        acc += add;
        rs[t] = acc;
        __syncthreads();
    }
    rs[t] = acc - v;   // exclusive
    __syncthreads();

    if (rbase + t < N_NODES) row_start[rbase + t] = bs + rs[t];
    if (k == 0 && t == 0) row_start[N_NODES] = NNZ;

    cnt[t] = 0;
    __syncthreads();
    for (int i = bs + t; i < be; i += 512) {
        const int2 rc = brc[i];
        const int lr = rc.x - rbase;
        const int pos = bs + rs[lr] + atomicAdd(&cnt[lr], 1);
        packed[pos] = make_int2(rc.y, __float_as_int(bv[i]));
    }
}

// ---------------------------------------------------------------------------
// SpMM, gather-form: one wave per row, lane = dim element. No atomics.
// ---------------------------------------------------------------------------
__global__ __launch_bounds__(256) void spmm_csr(const int* __restrict__ row_start,
                                                const int2* __restrict__ packed,
                                                const float* __restrict__ x,
                                                float* __restrict__ y) {
    const int row  = blockIdx.x * 4 + (threadIdx.x >> 6);
    const int lane = threadIdx.x & 63;
    if (row >= N_NODES) return;
    const int s = row_start[row];
    const int e = row_start[row + 1];
    float acc = 0.f;
    int i = s;
    for (; i + 4 <= e; i += 4) {
        const int2 p0 = packed[i + 0];
        const int2 p1 = packed[i + 1];
        const int2 p2 = packed[i + 2];
        const int2 p3 = packed[i + 3];
        const float x0 = x[(size_t)p0.x * DIM + lane];
        const float x1 = x[(size_t)p1.x * DIM + lane];
        const float x2 = x[(size_t)p2.x * DIM + lane];
        const float x3 = x[(size_t)p3.x * DIM + lane];
        acc = fmaf(__int_as_float(p0.y), x0, acc);
        acc = fmaf(__int_as_float(p1.y), x1, acc);
        acc = fmaf(__int_as_float(p2.y), x2, acc);
        acc = fmaf(__int_as_float(p3.y), x3, acc);
    }
    for (; i < e; ++i) {
        const int2 p = packed[i];
        acc = fmaf(__int_as_float(p.y), x[(size_t)p.x * DIM + lane], acc);
    }
    y[(size_t)row * DIM + lane] = acc;
}

// ---------------------------------------------------------------------------
// Layer-3: only batch rows, accumulate straight into uacc/iacc
// ---------------------------------------------------------------------------
__global__ __launch_bounds__(256) void spmm_batch_final(const int* __restrict__ row_start,
                                                        const int2* __restrict__ packed,
                                                        const float* __restrict__ x,
                                                        const int* __restrict__ users,
                                                        const int* __restrict__ items,
                                                        float* __restrict__ uacc,
                                                        float* __restrict__ iacc) {
    const int w    = blockIdx.x * 4 + (threadIdx.x >> 6);   // [0, 2*BATCH)
    const int lane = threadIdx.x & 63;
    if (w >= 2 * BATCH) return;
    const int b = w >> 1;
    const int isItem = w & 1;
    const int row = isItem ? (NUM_USERS + items[b]) : users[b];
    const int s = row_start[row];
    const int e = row_start[row + 1];
    float acc = 0.f;
    int i = s;
    for (; i + 4 <= e; i += 4) {
        const int2 p0 = packed[i + 0];
        const int2 p1 = packed[i + 1];
        const int2 p2 = packed[i + 2];
        const int2 p3 = packed[i + 3];
        const float x0 = x[(size_t)p0.x * DIM + lane];
        const float x1 = x[(size_t)p1.x * DIM + lane];
        const float x2 = x[(size_t)p2.x * DIM + lane];
        const float x3 = x[(size_t)p3.x * DIM + lane];
        acc = fmaf(__int_as_float(p0.y), x0, acc);
        acc = fmaf(__int_as_float(p1.y), x1, acc);
        acc = fmaf(__int_as_float(p2.y), x2, acc);
        acc = fmaf(__int_as_float(p3.y), x3, acc);
    }
    for (; i < e; ++i) {
        const int2 p = packed[i];
        acc = fmaf(__int_as_float(p.y), x[(size_t)p.x * DIM + lane], acc);
    }
    float* dst = isItem ? iacc : uacc;
    dst[(size_t)b * DIM + lane] += acc;
}

// ---------------------------------------------------------------------------
// uacc/iacc += y at the batch rows (layers 1 and 2)
// ---------------------------------------------------------------------------
__global__ void gather_add(const int* __restrict__ users,
                           const int* __restrict__ items,
                           const float4* __restrict__ y,
                           float4* __restrict__ uacc,
                           float4* __restrict__ iacc) {
    const int total = BATCH * (DIM / 4);
    int i = blockIdx.x * blockDim.x + threadIdx.x;
    if (i >= total) return;
    const int b = i >> 4;
    const int sub = i & 15;
    const int un = users[b];
    const int in = NUM_USERS + items[b];
    float4 a = uacc[i];
    const float4 yu = y[un * (DIM / 4) + sub];
    a.x += yu.x; a.y += yu.y; a.z += yu.z; a.w += yu.w;
    uacc[i] = a;
    float4 c = iacc[i];
    const float4 yi = y[in * (DIM / 4) + sub];
    c.x += yi.x; c.y += yi.y; c.z += yi.z; c.w += yi.w;
    iacc[i] = c;
}

// ---------------------------------------------------------------------------
// gamma[b] = dot(uacc[b], iacc[b]) / 16
// ---------------------------------------------------------------------------
__global__ void dot_out(const float* __restrict__ uacc,
                        const float* __restrict__ iacc,
                        float* __restrict__ gamma) {
    const int b = blockIdx.x * (blockDim.x / 64) + (threadIdx.x / 64);
    const int lane = threadIdx.x & 63;
    if (b >= BATCH) return;
    float p = uacc[b * DIM + lane] * iacc[b * DIM + lane];
    #pragma unroll
    for (int off = 32; off > 0; off >>= 1) p += __shfl_down(p, off);
    if (lane == 0) gamma[b] = p * 0.0625f;
}

// ---------------------------------------------------------------------------
extern "C" void kernel_launch(void* const* d_in, const int* in_sizes, int n_in,
                              void* d_out, int out_size, void* d_ws, size_t ws_size,
                              hipStream_t stream) {
    const float* ue    = (const float*)d_in[0];
    const float* ie    = (const float*)d_in[1];
    const float* oe    = (const float*)d_in[2];
    const float* vals  = (const float*)d_in[3];
    const int*   rows  = (const int*)d_in[4];
    const int*   cols  = (const int*)d_in[5];
    const int*   users = (const int*)d_in[6];
    const int*   items = (const int*)d_in[7];
    float* out = (float*)d_out;

    // ---- workspace layout ----
    // bucketed edges (60 MB) are dead after bucket_to_csr; `cur` (43.52 MB)
    // is aliased on top of them (build_cur0 runs after pass 4).
    char* p = (char*)d_ws;
    int2*  brc = (int2*)p;                                   // 40 MB
    float* bv  = (float*)(p + (size_t)NNZ * sizeof(int2));   // 20 MB
    float* cur = (float*)p;                                  // 43.52 MB (alias)
    p += (size_t)NNZ * (sizeof(int2) + sizeof(float));       // 60 MB block
    float* nxt  = (float*)p;  p += (size_t)N_NODES * DIM * sizeof(float);  // 43.52 MB
    int2*  packed = (int2*)p; p += (size_t)NNZ * sizeof(int2);             // 40 MB
    int*   row_start   = (int*)p;  p += (size_t)(N_NODES + 4) * sizeof(int);
    int*   bucket_cnt  = (int*)p;  p += (size_t)NBUCK * sizeof(int);
    int*   bucket_base = (int*)p;  p += (size_t)(NBUCK + 4) * sizeof(int);
    int*   gcursor     = (int*)p;  p += (size_t)NBUCK * sizeof(int);
    float* uacc = (float*)p;  p += (size_t)BATCH * DIM * sizeof(float);    // 2.1 MB
    float* iacc = (float*)p;  p += (size_t)BATCH * DIM * sizeof(float);    // 2.1 MB

    // ---- CSR build (bucketed, write-local) ----
    hipMemsetAsync(bucket_cnt, 0, (size_t)NBUCK * sizeof(int), stream);
    bucket_hist<<<NBLK, 256, 0, stream>>>(rows, bucket_cnt);
    bucket_scan<<<1, 512, 0, stream>>>(bucket_cnt, bucket_base, gcursor);
    bucket_scatter<<<NBLK, 256, 0, stream>>>(rows, cols, vals, gcursor, brc, bv);
    bucket_to_csr<<<NBUCK, 512, 0, stream>>>(bucket_base, brc, bv, row_start, packed);

    // ---- node matrix (aliased over dead bucketed edges) + accumulator init ----
    build_cur0<<<2048, 256, 0, stream>>>(ue, ie, oe, (float4*)cur);
    init_acc<<<(BATCH * 16 + 255) / 256, 256, 0, stream>>>(users, items, ue, ie,
                                                           (float4*)uacc, (float4*)iacc);

    // ---- layers 1 and 2: full SpMM, accumulate batch rows ----
    for (int layer = 0; layer < 2; ++layer) {
        spmm_csr<<<(N_NODES + 3) / 4, 256, 0, stream>>>(row_start, packed, cur, nxt);
        gather_add<<<(BATCH * 16 + 255) / 256, 256, 0, stream>>>(users, items,
                                                                 (const float4*)nxt,
                                                                 (float4*)uacc, (float4*)iacc);
        float* t = cur; cur = nxt; nxt = t;
    }

    // ---- layer 3: only the batch rows ----
    spmm_batch_final<<<(2 * BATCH + 3) / 4, 256, 0, stream>>>(row_start, packed, cur,
                                                              users, items, uacc, iacc);

    // ---- output ----
    dot_out<<<BATCH / 4, 256, 0, stream>>>(uacc, iacc, out);
}

// Round 4
// 519.572 us; speedup vs baseline: 24.4444x; 1.2521x over previous
//
#include <hip/hip_runtime.h>

#define NUM_USERS 100000
#define NUM_ITEMS 50000
#define NUM_OTHERS 20000
#define N_NODES 170000   // NUM_USERS + NUM_ITEMS + NUM_OTHERS
#define DIM 64
#define NNZ 5000000
#define BATCH 8192

#define BSHIFT 10
#define RPB (1 << BSHIFT)                       // 1024 rows per bucket
#define NBUCK ((N_NODES + RPB - 1) / RPB)       // 167 buckets
#define COLMASK 0x3FFFF                         // 18 bits for col (N_NODES < 2^18)
#define NBLK 512                                // blocks for scatter pass
#define CHUNK ((NNZ + NBLK - 1) / NBLK)         // 9766 edges per block
#define HBLK 1024                               // blocks for hist pass
#define HCHUNK ((NNZ + HBLK - 1) / HBLK)

// fp32 -> bf16 round-to-nearest-even
static __device__ __forceinline__ unsigned short f2bf(float f) {
    unsigned u = __float_as_uint(f);
    u = (u + 0x7fff + ((u >> 16) & 1)) >> 16;
    return (unsigned short)u;
}
static __device__ __forceinline__ float bf2f(unsigned short u) {
    return __uint_as_float(((unsigned)u) << 16);
}

// ---------------------------------------------------------------------------
// cur0 = concat(user_emb, item_emb, other_emb)  -> bf16
// ---------------------------------------------------------------------------
__global__ void build_cur0(const float* __restrict__ ue,
                           const float* __restrict__ ie,
                           const float* __restrict__ oe,
                           ushort4* __restrict__ cur) {
    const int total = N_NODES * (DIM / 4);
    for (int i = blockIdx.x * blockDim.x + threadIdx.x; i < total;
         i += gridDim.x * blockDim.x) {
        const int node = i >> 4;
        const int sub  = i & 15;
        const float* src;
        if (node < NUM_USERS)                  src = ue + (size_t)node * DIM;
        else if (node < NUM_USERS + NUM_ITEMS) src = ie + (size_t)(node - NUM_USERS) * DIM;
        else                                   src = oe + (size_t)(node - NUM_USERS - NUM_ITEMS) * DIM;
        const float4 f = reinterpret_cast<const float4*>(src)[sub];
        ushort4 o;
        o.x = f2bf(f.x); o.y = f2bf(f.y); o.z = f2bf(f.z); o.w = f2bf(f.w);
        cur[i] = o;
    }
}

// ---------------------------------------------------------------------------
// batch accumulators start as layer-0 embeddings (fp32)
// ---------------------------------------------------------------------------
__global__ void init_acc(const int* __restrict__ users,
                         const int* __restrict__ items,
                         const float* __restrict__ ue,
                         const float* __restrict__ ie,
                         float4* __restrict__ uacc,
                         float4* __restrict__ iacc) {
    const int total = BATCH * (DIM / 4);
    int i = blockIdx.x * blockDim.x + threadIdx.x;
    if (i >= total) return;
    const int b = i >> 4;
    const int sub = i & 15;
    uacc[i] = reinterpret_cast<const float4*>(ue + (size_t)users[b] * DIM)[sub];
    iacc[i] = reinterpret_cast<const float4*>(ie + (size_t)items[b] * DIM)[sub];
}

// ---------------------------------------------------------------------------
// Pass 1: bucket histogram (LDS pre-aggregation)
// ---------------------------------------------------------------------------
__global__ __launch_bounds__(256) void bucket_hist(const int* __restrict__ rows,
                                                   int* __restrict__ bucket_cnt) {
    __shared__ int h[NBUCK];
    for (int i = threadIdx.x; i < NBUCK; i += 256) h[i] = 0;
    __syncthreads();
    const int s = blockIdx.x * HCHUNK;
    const int e = min(s + HCHUNK, NNZ);
    for (int i = s + threadIdx.x; i < e; i += 256)
        atomicAdd(&h[rows[i] >> BSHIFT], 1);
    __syncthreads();
    for (int i = threadIdx.x; i < NBUCK; i += 256)
        if (h[i]) atomicAdd(&bucket_cnt[i], h[i]);
}

// ---------------------------------------------------------------------------
// Pass 2: exclusive scan of 167 bucket counts (one block)
// ---------------------------------------------------------------------------
__global__ __launch_bounds__(256) void bucket_scan(const int* __restrict__ bucket_cnt,
                                                   int* __restrict__ bucket_base,
                                                   int* __restrict__ gcursor) {
    __shared__ int lds[256];
    const int t = threadIdx.x;
    const int v = (t < NBUCK) ? bucket_cnt[t] : 0;
    lds[t] = v;
    __syncthreads();
    int acc = v;
    for (int off = 1; off < 256; off <<= 1) {
        const int add = (t >= off) ? lds[t - off] : 0;
        __syncthreads();
        acc += add;
        lds[t] = acc;
        __syncthreads();
    }
    if (t < NBUCK) {
        const int ex = acc - v;
        bucket_base[t] = ex;
        gcursor[t] = ex;
    }
    if (t == 0) bucket_base[NBUCK] = NNZ;
}

// ---------------------------------------------------------------------------
// Pass 3: scatter edges into bucket-major order; one 8B int2 per edge:
//   .x = (local_row << 18) | col,  .y = val bits
// ---------------------------------------------------------------------------
__global__ __launch_bounds__(256) void bucket_scatter(const int* __restrict__ rows,
                                                      const int* __restrict__ cols,
                                                      const float* __restrict__ vals,
                                                      int* __restrict__ gcursor,
                                                      int2* __restrict__ bkt) {
    __shared__ int h[NBUCK];
    __shared__ int base[NBUCK];
    for (int i = threadIdx.x; i < NBUCK; i += 256) h[i] = 0;
    __syncthreads();
    const int s = blockIdx.x * CHUNK;
    const int e = min(s + CHUNK, NNZ);
    for (int i = s + threadIdx.x; i < e; i += 256)
        atomicAdd(&h[rows[i] >> BSHIFT], 1);
    __syncthreads();
    for (int i = threadIdx.x; i < NBUCK; i += 256)
        base[i] = h[i] ? atomicAdd(&gcursor[i], h[i]) : 0;
    __syncthreads();
    for (int i = threadIdx.x; i < NBUCK; i += 256) h[i] = 0;
    __syncthreads();
    for (int i = s + threadIdx.x; i < e; i += 256) {
        const int r  = rows[i];
        const int bk = r >> BSHIFT;
        const int lr = r & (RPB - 1);
        const int pos = base[bk] + atomicAdd(&h[bk], 1);
        bkt[pos] = make_int2((lr << 18) | cols[i], __float_as_int(vals[i]));
    }
}

// ---------------------------------------------------------------------------
// Pass 4: per-bucket counting sort -> final CSR (packed (col,val)) + row_start
// ---------------------------------------------------------------------------
__global__ __launch_bounds__(512) void bucket_to_csr(const int* __restrict__ bucket_base,
                                                     const int2* __restrict__ bkt,
                                                     int* __restrict__ row_start,
                                                     int2* __restrict__ packed) {
    __shared__ int cnt[RPB];
    __shared__ int rs[RPB];
    __shared__ int tsum[512];
    const int k = blockIdx.x;
    const int rbase = k << BSHIFT;
    const int bs = bucket_base[k];
    const int be = bucket_base[k + 1];
    const int t = threadIdx.x;

    cnt[t] = 0; cnt[t + 512] = 0;
    __syncthreads();
    for (int i = bs + t; i < be; i += 512)
        atomicAdd(&cnt[bkt[i].x >> 18], 1);
    __syncthreads();

    // exclusive scan of 1024 counts: 2 per thread + Hillis-Steele over totals
    const int v0 = cnt[2 * t];
    const int v1 = cnt[2 * t + 1];
    int acc = v0 + v1;
    tsum[t] = acc;
    __syncthreads();
    for (int off = 1; off < 512; off <<= 1) {
        const int add = (t >= off) ? tsum[t - off] : 0;
        __syncthreads();
        acc += add;
        tsum[t] = acc;
        __syncthreads();
    }
    const int excl = acc - (v0 + v1);
    rs[2 * t]     = excl;
    rs[2 * t + 1] = excl + v0;
    if (rbase + 2 * t < N_NODES)     row_start[rbase + 2 * t]     = bs + excl;
    if (rbase + 2 * t + 1 < N_NODES) row_start[rbase + 2 * t + 1] = bs + excl + v0;
    if (k == 0 && t == 0) row_start[N_NODES] = NNZ;

    cnt[t] = 0; cnt[t + 512] = 0;
    __syncthreads();
    for (int i = bs + t; i < be; i += 512) {
        const int2 pk = bkt[i];
        const int lr = pk.x >> 18;
        const int pos = bs + rs[lr] + atomicAdd(&cnt[lr], 1);
        packed[pos] = make_int2(pk.x & COLMASK, pk.y);
    }
}

// ---------------------------------------------------------------------------
// SpMM, gather-form: one wave per row, lane = dim element. bf16 x, bf16 y.
// ---------------------------------------------------------------------------
__global__ __launch_bounds__(256) void spmm_csr(const int* __restrict__ row_start,
                                                const int2* __restrict__ packed,
                                                const unsigned short* __restrict__ x,
                                                unsigned short* __restrict__ y) {
    const int row  = blockIdx.x * 4 + (threadIdx.x >> 6);
    const int lane = threadIdx.x & 63;
    if (row >= N_NODES) return;
    const int s = row_start[row];
    const int e = row_start[row + 1];
    float acc = 0.f;
    int i = s;
    for (; i + 4 <= e; i += 4) {
        const int2 p0 = packed[i + 0];
        const int2 p1 = packed[i + 1];
        const int2 p2 = packed[i + 2];
        const int2 p3 = packed[i + 3];
        const float x0 = bf2f(x[(size_t)p0.x * DIM + lane]);
        const float x1 = bf2f(x[(size_t)p1.x * DIM + lane]);
        const float x2 = bf2f(x[(size_t)p2.x * DIM + lane]);
        const float x3 = bf2f(x[(size_t)p3.x * DIM + lane]);
        acc = fmaf(__int_as_float(p0.y), x0, acc);
        acc = fmaf(__int_as_float(p1.y), x1, acc);
        acc = fmaf(__int_as_float(p2.y), x2, acc);
        acc = fmaf(__int_as_float(p3.y), x3, acc);
    }
    for (; i < e; ++i) {
        const int2 p = packed[i];
        acc = fmaf(__int_as_float(p.y), bf2f(x[(size_t)p.x * DIM + lane]), acc);
    }
    y[(size_t)row * DIM + lane] = f2bf(acc);
}

// ---------------------------------------------------------------------------
// Layer-3: only batch rows, accumulate straight into fp32 uacc/iacc
// ---------------------------------------------------------------------------
__global__ __launch_bounds__(256) void spmm_batch_final(const int* __restrict__ row_start,
                                                        const int2* __restrict__ packed,
                                                        const unsigned short* __restrict__ x,
                                                        const int* __restrict__ users,
                                                        const int* __restrict__ items,
                                                        float* __restrict__ uacc,
                                                        float* __restrict__ iacc) {
    const int w    = blockIdx.x * 4 + (threadIdx.x >> 6);   // [0, 2*BATCH)
    const int lane = threadIdx.x & 63;
    if (w >= 2 * BATCH) return;
    const int b = w >> 1;
    const int isItem = w & 1;
    const int row = isItem ? (NUM_USERS + items[b]) : users[b];
    const int s = row_start[row];
    const int e = row_start[row + 1];
    float acc = 0.f;
    int i = s;
    for (; i + 4 <= e; i += 4) {
        const int2 p0 = packed[i + 0];
        const int2 p1 = packed[i + 1];
        const int2 p2 = packed[i + 2];
        const int2 p3 = packed[i + 3];
        const float x0 = bf2f(x[(size_t)p0.x * DIM + lane]);
        const float x1 = bf2f(x[(size_t)p1.x * DIM + lane]);
        const float x2 = bf2f(x[(size_t)p2.x * DIM + lane]);
        const float x3 = bf2f(x[(size_t)p3.x * DIM + lane]);
        acc = fmaf(__int_as_float(p0.y), x0, acc);
        acc = fmaf(__int_as_float(p1.y), x1, acc);
        acc = fmaf(__int_as_float(p2.y), x2, acc);
        acc = fmaf(__int_as_float(p3.y), x3, acc);
    }
    for (; i < e; ++i) {
        const int2 p = packed[i];
        acc = fmaf(__int_as_float(p.y), bf2f(x[(size_t)p.x * DIM + lane]), acc);
    }
    float* dst = isItem ? iacc : uacc;
    dst[(size_t)b * DIM + lane] += acc;
}

// ---------------------------------------------------------------------------
// uacc/iacc += y (bf16) at the batch rows (layers 1 and 2)
// ---------------------------------------------------------------------------
__global__ void gather_add(const int* __restrict__ users,
                           const int* __restrict__ items,
                           const unsigned short* __restrict__ y,
                           float4* __restrict__ uacc,
                           float4* __restrict__ iacc) {
    const int total = BATCH * (DIM / 4);
    int i = blockIdx.x * blockDim.x + threadIdx.x;
    if (i >= total) return;
    const int b = i >> 4;
    const int sub = i & 15;
    const int un = users[b];
    const int in = NUM_USERS + items[b];
    float4 a = uacc[i];
    const ushort4 yu = *reinterpret_cast<const ushort4*>(y + (size_t)un * DIM + sub * 4);
    a.x += bf2f(yu.x); a.y += bf2f(yu.y); a.z += bf2f(yu.z); a.w += bf2f(yu.w);
    uacc[i] = a;
    float4 c = iacc[i];
    const ushort4 yi = *reinterpret_cast<const ushort4*>(y + (size_t)in * DIM + sub * 4);
    c.x += bf2f(yi.x); c.y += bf2f(yi.y); c.z += bf2f(yi.z); c.w += bf2f(yi.w);
    iacc[i] = c;
}

// ---------------------------------------------------------------------------
// gamma[b] = dot(uacc[b], iacc[b]) / 16
// ---------------------------------------------------------------------------
__global__ void dot_out(const float* __restrict__ uacc,
                        const float* __restrict__ iacc,
                        float* __restrict__ gamma) {
    const int b = blockIdx.x * (blockDim.x / 64) + (threadIdx.x / 64);
    const int lane = threadIdx.x & 63;
    if (b >= BATCH) return;
    float p = uacc[b * DIM + lane] * iacc[b * DIM + lane];
    #pragma unroll
    for (int off = 32; off > 0; off >>= 1) p += __shfl_down(p, off);
    if (lane == 0) gamma[b] = p * 0.0625f;
}

// ---------------------------------------------------------------------------
extern "C" void kernel_launch(void* const* d_in, const int* in_sizes, int n_in,
                              void* d_out, int out_size, void* d_ws, size_t ws_size,
                              hipStream_t stream) {
    const float* ue    = (const float*)d_in[0];
    const float* ie    = (const float*)d_in[1];
    const float* oe    = (const float*)d_in[2];
    const float* vals  = (const float*)d_in[3];
    const int*   rows  = (const int*)d_in[4];
    const int*   cols  = (const int*)d_in[5];
    const int*   users = (const int*)d_in[6];
    const int*   items = (const int*)d_in[7];
    float* out = (float*)d_out;

    // ---- workspace layout ----
    // bucketed edges (40 MB) are dead after bucket_to_csr; cur (bf16, 21.8 MB)
    // is aliased on top (build_cur0 runs after pass 4).
    char* p = (char*)d_ws;
    int2* bkt = (int2*)p;                                      // 40 MB
    unsigned short* cur = (unsigned short*)p;                  // 21.76 MB (alias)
    p += (size_t)NNZ * sizeof(int2);
    unsigned short* nxt = (unsigned short*)p;                  // 21.76 MB
    p += (size_t)N_NODES * DIM * sizeof(unsigned short);
    int2* packed = (int2*)p;  p += (size_t)NNZ * sizeof(int2); // 40 MB
    int* row_start   = (int*)p;  p += (size_t)(N_NODES + 4) * sizeof(int);
    int* bucket_cnt  = (int*)p;  p += (size_t)(NBUCK + 4) * sizeof(int);
    int* bucket_base = (int*)p;  p += (size_t)(NBUCK + 4) * sizeof(int);
    int* gcursor     = (int*)p;  p += (size_t)(NBUCK + 4) * sizeof(int);
    float* uacc = (float*)p;  p += (size_t)BATCH * DIM * sizeof(float);
    float* iacc = (float*)p;  p += (size_t)BATCH * DIM * sizeof(float);

    // ---- CSR build (bucketed, write-local) ----
    hipMemsetAsync(bucket_cnt, 0, (size_t)NBUCK * sizeof(int), stream);
    bucket_hist<<<HBLK, 256, 0, stream>>>(rows, bucket_cnt);
    bucket_scan<<<1, 256, 0, stream>>>(bucket_cnt, bucket_base, gcursor);
    bucket_scatter<<<NBLK, 256, 0, stream>>>(rows, cols, vals, gcursor, bkt);
    bucket_to_csr<<<NBUCK, 512, 0, stream>>>(bucket_base, bkt, row_start, packed);

    // ---- node matrix (aliased over dead bucketed edges) + accumulator init ----
    build_cur0<<<2048, 256, 0, stream>>>(ue, ie, oe, (ushort4*)cur);
    init_acc<<<(BATCH * 16 + 255) / 256, 256, 0, stream>>>(users, items, ue, ie,
                                                           (float4*)uacc, (float4*)iacc);

    // ---- layers 1 and 2: full SpMM, accumulate batch rows ----
    for (int layer = 0; layer < 2; ++layer) {
        spmm_csr<<<(N_NODES + 3) / 4, 256, 0, stream>>>(row_start, packed, cur, nxt);
        gather_add<<<(BATCH * 16 + 255) / 256, 256, 0, stream>>>(users, items, nxt,
                                                                 (float4*)uacc, (float4*)iacc);
        unsigned short* t = cur; cur = nxt; nxt = t;
    }

    // ---- layer 3: only the batch rows ----
    spmm_batch_final<<<(2 * BATCH + 3) / 4, 256, 0, stream>>>(row_start, packed, cur,
                                                              users, items, uacc, iacc);

    // ---- output ----
    dot_out<<<BATCH / 4, 256, 0, stream>>>(uacc, iacc, out);
}

// Round 5
// 399.684 us; speedup vs baseline: 31.7766x; 1.3000x over previous
//
#include <hip/hip_runtime.h>

#define NUM_USERS 100000
#define NUM_ITEMS 50000
#define NUM_OTHERS 20000
#define N_NODES 170000   // NUM_USERS + NUM_ITEMS + NUM_OTHERS
#define DIM 64
#define NNZ 5000000
#define BATCH 8192

#define BSHIFT 10
#define RPB (1 << BSHIFT)                       // 1024 rows per bucket
#define NBUCK ((N_NODES + RPB - 1) / RPB)       // 167 buckets
#define COLMASK 0x3FFFF                         // 18 bits for col (N_NODES < 2^18)
#define NBLK 512                                // blocks for scatter pass
#define CHUNK ((NNZ + NBLK - 1) / NBLK)         // 9766 edges per block
#define HBLK 1024                               // blocks for hist pass
#define HCHUNK ((NNZ + HBLK - 1) / HBLK)

// fp32 -> bf16 round-to-nearest-even
static __device__ __forceinline__ unsigned f2bf(float f) {
    unsigned u = __float_as_uint(f);
    u = (u + 0x7fff + ((u >> 16) & 1)) >> 16;
    return u;
}
static __device__ __forceinline__ float bflo(unsigned u) {   // low ushort -> f32
    return __uint_as_float(u << 16);
}
static __device__ __forceinline__ float bfhi(unsigned u) {   // high ushort -> f32
    return __uint_as_float(u & 0xFFFF0000u);
}

// ---------------------------------------------------------------------------
// cur0 = concat(user_emb, item_emb, other_emb)  -> bf16
// ---------------------------------------------------------------------------
__global__ void build_cur0(const float* __restrict__ ue,
                           const float* __restrict__ ie,
                           const float* __restrict__ oe,
                           ushort4* __restrict__ cur) {
    const int total = N_NODES * (DIM / 4);
    for (int i = blockIdx.x * blockDim.x + threadIdx.x; i < total;
         i += gridDim.x * blockDim.x) {
        const int node = i >> 4;
        const int sub  = i & 15;
        const float* src;
        if (node < NUM_USERS)                  src = ue + (size_t)node * DIM;
        else if (node < NUM_USERS + NUM_ITEMS) src = ie + (size_t)(node - NUM_USERS) * DIM;
        else                                   src = oe + (size_t)(node - NUM_USERS - NUM_ITEMS) * DIM;
        const float4 f = reinterpret_cast<const float4*>(src)[sub];
        ushort4 o;
        o.x = (unsigned short)f2bf(f.x); o.y = (unsigned short)f2bf(f.y);
        o.z = (unsigned short)f2bf(f.z); o.w = (unsigned short)f2bf(f.w);
        cur[i] = o;
    }
}

// ---------------------------------------------------------------------------
// batch accumulators start as layer-0 embeddings (fp32)
// ---------------------------------------------------------------------------
__global__ void init_acc(const int* __restrict__ users,
                         const int* __restrict__ items,
                         const float* __restrict__ ue,
                         const float* __restrict__ ie,
                         float4* __restrict__ uacc,
                         float4* __restrict__ iacc) {
    const int total = BATCH * (DIM / 4);
    int i = blockIdx.x * blockDim.x + threadIdx.x;
    if (i >= total) return;
    const int b = i >> 4;
    const int sub = i & 15;
    uacc[i] = reinterpret_cast<const float4*>(ue + (size_t)users[b] * DIM)[sub];
    iacc[i] = reinterpret_cast<const float4*>(ie + (size_t)items[b] * DIM)[sub];
}

// ---------------------------------------------------------------------------
// Pass 1: bucket histogram (LDS pre-aggregation)
// ---------------------------------------------------------------------------
__global__ __launch_bounds__(256) void bucket_hist(const int* __restrict__ rows,
                                                   int* __restrict__ bucket_cnt) {
    __shared__ int h[NBUCK];
    for (int i = threadIdx.x; i < NBUCK; i += 256) h[i] = 0;
    __syncthreads();
    const int s = blockIdx.x * HCHUNK;
    const int e = min(s + HCHUNK, NNZ);
    for (int i = s + threadIdx.x; i < e; i += 256)
        atomicAdd(&h[rows[i] >> BSHIFT], 1);
    __syncthreads();
    for (int i = threadIdx.x; i < NBUCK; i += 256)
        if (h[i]) atomicAdd(&bucket_cnt[i], h[i]);
}

// ---------------------------------------------------------------------------
// Pass 2: exclusive scan of 167 bucket counts (one block)
// ---------------------------------------------------------------------------
__global__ __launch_bounds__(256) void bucket_scan(const int* __restrict__ bucket_cnt,
                                                   int* __restrict__ bucket_base,
                                                   int* __restrict__ gcursor) {
    __shared__ int lds[256];
    const int t = threadIdx.x;
    const int v = (t < NBUCK) ? bucket_cnt[t] : 0;
    lds[t] = v;
    __syncthreads();
    int acc = v;
    for (int off = 1; off < 256; off <<= 1) {
        const int add = (t >= off) ? lds[t - off] : 0;
        __syncthreads();
        acc += add;
        lds[t] = acc;
        __syncthreads();
    }
    if (t < NBUCK) {
        const int ex = acc - v;
        bucket_base[t] = ex;
        gcursor[t] = ex;
    }
    if (t == 0) bucket_base[NBUCK] = NNZ;
}

// ---------------------------------------------------------------------------
// Pass 3: scatter edges into bucket-major order; one 8B int2 per edge:
//   .x = (local_row << 18) | col,  .y = val bits
// ---------------------------------------------------------------------------
__global__ __launch_bounds__(256) void bucket_scatter(const int* __restrict__ rows,
                                                      const int* __restrict__ cols,
                                                      const float* __restrict__ vals,
                                                      int* __restrict__ gcursor,
                                                      int2* __restrict__ bkt) {
    __shared__ int h[NBUCK];
    __shared__ int base[NBUCK];
    for (int i = threadIdx.x; i < NBUCK; i += 256) h[i] = 0;
    __syncthreads();
    const int s = blockIdx.x * CHUNK;
    const int e = min(s + CHUNK, NNZ);
    for (int i = s + threadIdx.x; i < e; i += 256)
        atomicAdd(&h[rows[i] >> BSHIFT], 1);
    __syncthreads();
    for (int i = threadIdx.x; i < NBUCK; i += 256)
        base[i] = h[i] ? atomicAdd(&gcursor[i], h[i]) : 0;
    __syncthreads();
    for (int i = threadIdx.x; i < NBUCK; i += 256) h[i] = 0;
    __syncthreads();
    for (int i = s + threadIdx.x; i < e; i += 256) {
        const int r  = rows[i];
        const int bk = r >> BSHIFT;
        const int lr = r & (RPB - 1);
        const int pos = base[bk] + atomicAdd(&h[bk], 1);
        bkt[pos] = make_int2((lr << 18) | cols[i], __float_as_int(vals[i]));
    }
}

// ---------------------------------------------------------------------------
// Pass 4: per-bucket counting sort -> final CSR (packed (col,val)) + row_start
// ---------------------------------------------------------------------------
__global__ __launch_bounds__(512) void bucket_to_csr(const int* __restrict__ bucket_base,
                                                     const int2* __restrict__ bkt,
                                                     int* __restrict__ row_start,
                                                     int2* __restrict__ packed) {
    __shared__ int cnt[RPB];
    __shared__ int rs[RPB];
    __shared__ int tsum[512];
    const int k = blockIdx.x;
    const int rbase = k << BSHIFT;
    const int bs = bucket_base[k];
    const int be = bucket_base[k + 1];
    const int t = threadIdx.x;

    cnt[t] = 0; cnt[t + 512] = 0;
    __syncthreads();
    for (int i = bs + t; i < be; i += 512)
        atomicAdd(&cnt[bkt[i].x >> 18], 1);
    __syncthreads();

    // exclusive scan of 1024 counts: 2 per thread + Hillis-Steele over totals
    const int v0 = cnt[2 * t];
    const int v1 = cnt[2 * t + 1];
    int acc = v0 + v1;
    tsum[t] = acc;
    __syncthreads();
    for (int off = 1; off < 512; off <<= 1) {
        const int add = (t >= off) ? tsum[t - off] : 0;
        __syncthreads();
        acc += add;
        tsum[t] = acc;
        __syncthreads();
    }
    const int excl = acc - (v0 + v1);
    rs[2 * t]     = excl;
    rs[2 * t + 1] = excl + v0;
    if (rbase + 2 * t < N_NODES)     row_start[rbase + 2 * t]     = bs + excl;
    if (rbase + 2 * t + 1 < N_NODES) row_start[rbase + 2 * t + 1] = bs + excl + v0;
    if (k == 0 && t == 0) row_start[N_NODES] = NNZ;

    cnt[t] = 0; cnt[t + 512] = 0;
    __syncthreads();
    for (int i = bs + t; i < be; i += 512) {
        const int2 pk = bkt[i];
        const int lr = pk.x >> 18;
        const int pos = bs + rs[lr] + atomicAdd(&cnt[lr], 1);
        packed[pos] = make_int2(pk.x & COLMASK, pk.y);
    }
}

// ---------------------------------------------------------------------------
// SpMM gather, 8 lanes per edge: each lane loads 16B (8 bf16 dims) of x[col].
// One wave = 1 row, 8 edge-groups, 16 edges in flight per iteration.
// Butterfly shfl_xor(8,16,32) combines edge-groups at the end.
// ---------------------------------------------------------------------------
__global__ __launch_bounds__(256) void spmm_csr8(const int* __restrict__ row_start,
                                                 const unsigned long long* __restrict__ packed,
                                                 const unsigned short* __restrict__ x,
                                                 unsigned short* __restrict__ y) {
    const int row  = blockIdx.x * 4 + (threadIdx.x >> 6);
    const int lane = threadIdx.x & 63;
    if (row >= N_NODES) return;
    const int s = row_start[row];
    const int e = row_start[row + 1];
    const int g  = lane >> 3;          // edge group 0..7
    const int d8 = (lane & 7) * 8;     // dim base 0..56

    float a0 = 0, a1 = 0, a2 = 0, a3 = 0, a4 = 0, a5 = 0, a6 = 0, a7 = 0;

    for (int i = s; i < e; i += 16) {
        const int j0 = i + g;
        const int j1 = i + 8 + g;
        const unsigned long long p0 = __builtin_nontemporal_load(packed + j0);
        const unsigned long long p1 = __builtin_nontemporal_load(packed + j1);
        const int   c0 = (int)(p0 & 0xFFFFFFFFu);
        const int   c1 = (int)(p1 & 0xFFFFFFFFu);
        const float v0 = (j0 < e) ? __uint_as_float((unsigned)(p0 >> 32)) : 0.f;
        const float v1 = (j1 < e) ? __uint_as_float((unsigned)(p1 >> 32)) : 0.f;
        const uint4 xv0 = *reinterpret_cast<const uint4*>(x + c0 * DIM + d8);
        const uint4 xv1 = *reinterpret_cast<const uint4*>(x + c1 * DIM + d8);
        a0 = fmaf(v0, bflo(xv0.x), a0);  a1 = fmaf(v0, bfhi(xv0.x), a1);
        a2 = fmaf(v0, bflo(xv0.y), a2);  a3 = fmaf(v0, bfhi(xv0.y), a3);
        a4 = fmaf(v0, bflo(xv0.z), a4);  a5 = fmaf(v0, bfhi(xv0.z), a5);
        a6 = fmaf(v0, bflo(xv0.w), a6);  a7 = fmaf(v0, bfhi(xv0.w), a7);
        a0 = fmaf(v1, bflo(xv1.x), a0);  a1 = fmaf(v1, bfhi(xv1.x), a1);
        a2 = fmaf(v1, bflo(xv1.y), a2);  a3 = fmaf(v1, bfhi(xv1.y), a3);
        a4 = fmaf(v1, bflo(xv1.z), a4);  a5 = fmaf(v1, bfhi(xv1.z), a5);
        a6 = fmaf(v1, bflo(xv1.w), a6);  a7 = fmaf(v1, bfhi(xv1.w), a7);
    }

    #pragma unroll
    for (int off = 8; off < 64; off <<= 1) {
        a0 += __shfl_xor(a0, off); a1 += __shfl_xor(a1, off);
        a2 += __shfl_xor(a2, off); a3 += __shfl_xor(a3, off);
        a4 += __shfl_xor(a4, off); a5 += __shfl_xor(a5, off);
        a6 += __shfl_xor(a6, off); a7 += __shfl_xor(a7, off);
    }

    if (lane < 8) {
        uint4 o;
        o.x = f2bf(a0) | (f2bf(a1) << 16);
        o.y = f2bf(a2) | (f2bf(a3) << 16);
        o.z = f2bf(a4) | (f2bf(a5) << 16);
        o.w = f2bf(a6) | (f2bf(a7) << 16);
        *reinterpret_cast<uint4*>(y + row * DIM + lane * 8) = o;
    }
}

// ---------------------------------------------------------------------------
// Layer-3: only batch rows, same 8-wide gather, accumulate into fp32 uacc/iacc
// ---------------------------------------------------------------------------
__global__ __launch_bounds__(256) void spmm_batch_final8(const int* __restrict__ row_start,
                                                         const unsigned long long* __restrict__ packed,
                                                         const unsigned short* __restrict__ x,
                                                         const int* __restrict__ users,
                                                         const int* __restrict__ items,
                                                         float* __restrict__ uacc,
                                                         float* __restrict__ iacc) {
    const int w    = blockIdx.x * 4 + (threadIdx.x >> 6);   // [0, 2*BATCH)
    const int lane = threadIdx.x & 63;
    if (w >= 2 * BATCH) return;
    const int b = w >> 1;
    const int isItem = w & 1;
    const int row = isItem ? (NUM_USERS + items[b]) : users[b];
    const int s = row_start[row];
    const int e = row_start[row + 1];
    const int g  = lane >> 3;
    const int d8 = (lane & 7) * 8;

    float a0 = 0, a1 = 0, a2 = 0, a3 = 0, a4 = 0, a5 = 0, a6 = 0, a7 = 0;

    for (int i = s; i < e; i += 16) {
        const int j0 = i + g;
        const int j1 = i + 8 + g;
        const unsigned long long p0 = __builtin_nontemporal_load(packed + j0);
        const unsigned long long p1 = __builtin_nontemporal_load(packed + j1);
        const int   c0 = (int)(p0 & 0xFFFFFFFFu);
        const int   c1 = (int)(p1 & 0xFFFFFFFFu);
        const float v0 = (j0 < e) ? __uint_as_float((unsigned)(p0 >> 32)) : 0.f;
        const float v1 = (j1 < e) ? __uint_as_float((unsigned)(p1 >> 32)) : 0.f;
        const uint4 xv0 = *reinterpret_cast<const uint4*>(x + c0 * DIM + d8);
        const uint4 xv1 = *reinterpret_cast<const uint4*>(x + c1 * DIM + d8);
        a0 = fmaf(v0, bflo(xv0.x), a0);  a1 = fmaf(v0, bfhi(xv0.x), a1);
        a2 = fmaf(v0, bflo(xv0.y), a2);  a3 = fmaf(v0, bfhi(xv0.y), a3);
        a4 = fmaf(v0, bflo(xv0.z), a4);  a5 = fmaf(v0, bfhi(xv0.z), a5);
        a6 = fmaf(v0, bflo(xv0.w), a6);  a7 = fmaf(v0, bfhi(xv0.w), a7);
        a0 = fmaf(v1, bflo(xv1.x), a0);  a1 = fmaf(v1, bfhi(xv1.x), a1);
        a2 = fmaf(v1, bflo(xv1.y), a2);  a3 = fmaf(v1, bfhi(xv1.y), a3);
        a4 = fmaf(v1, bflo(xv1.z), a4);  a5 = fmaf(v1, bfhi(xv1.z), a5);
        a6 = fmaf(v1, bflo(xv1.w), a6);  a7 = fmaf(v1, bfhi(xv1.w), a7);
    }

    #pragma unroll
    for (int off = 8; off < 64; off <<= 1) {
        a0 += __shfl_xor(a0, off); a1 += __shfl_xor(a1, off);
        a2 += __shfl_xor(a2, off); a3 += __shfl_xor(a3, off);
        a4 += __shfl_xor(a4, off); a5 += __shfl_xor(a5, off);
        a6 += __shfl_xor(a6, off); a7 += __shfl_xor(a7, off);
    }

    if (lane < 8) {
        float* dst = (isItem ? iacc : uacc) + (size_t)b * DIM + lane * 8;
        float4 q0 = reinterpret_cast<float4*>(dst)[0];
        float4 q1 = reinterpret_cast<float4*>(dst)[1];
        q0.x += a0; q0.y += a1; q0.z += a2; q0.w += a3;
        q1.x += a4; q1.y += a5; q1.z += a6; q1.w += a7;
        reinterpret_cast<float4*>(dst)[0] = q0;
        reinterpret_cast<float4*>(dst)[1] = q1;
    }
}

// ---------------------------------------------------------------------------
// uacc/iacc += y (bf16) at the batch rows (layers 1 and 2)
// ---------------------------------------------------------------------------
__global__ void gather_add(const int* __restrict__ users,
                           const int* __restrict__ items,
                           const unsigned short* __restrict__ y,
                           float4* __restrict__ uacc,
                           float4* __restrict__ iacc) {
    const int total = BATCH * (DIM / 4);
    int i = blockIdx.x * blockDim.x + threadIdx.x;
    if (i >= total) return;
    const int b = i >> 4;
    const int sub = i & 15;
    const int un = users[b];
    const int in = NUM_USERS + items[b];
    float4 a = uacc[i];
    const ushort4 yu = *reinterpret_cast<const ushort4*>(y + (size_t)un * DIM + sub * 4);
    a.x += bflo(yu.x); a.y += bflo(yu.y); a.z += bflo(yu.z); a.w += bflo(yu.w);
    uacc[i] = a;
    float4 c = iacc[i];
    const ushort4 yi = *reinterpret_cast<const ushort4*>(y + (size_t)in * DIM + sub * 4);
    c.x += bflo(yi.x); c.y += bflo(yi.y); c.z += bflo(yi.z); c.w += bflo(yi.w);
    iacc[i] = c;
}

// ---------------------------------------------------------------------------
// gamma[b] = dot(uacc[b], iacc[b]) / 16
// ---------------------------------------------------------------------------
__global__ void dot_out(const float* __restrict__ uacc,
                        const float* __restrict__ iacc,
                        float* __restrict__ gamma) {
    const int b = blockIdx.x * (blockDim.x / 64) + (threadIdx.x / 64);
    const int lane = threadIdx.x & 63;
    if (b >= BATCH) return;
    float p = uacc[b * DIM + lane] * iacc[b * DIM + lane];
    #pragma unroll
    for (int off = 32; off > 0; off >>= 1) p += __shfl_down(p, off);
    if (lane == 0) gamma[b] = p * 0.0625f;
}

// ---------------------------------------------------------------------------
extern "C" void kernel_launch(void* const* d_in, const int* in_sizes, int n_in,
                              void* d_out, int out_size, void* d_ws, size_t ws_size,
                              hipStream_t stream) {
    const float* ue    = (const float*)d_in[0];
    const float* ie    = (const float*)d_in[1];
    const float* oe    = (const float*)d_in[2];
    const float* vals  = (const float*)d_in[3];
    const int*   rows  = (const int*)d_in[4];
    const int*   cols  = (const int*)d_in[5];
    const int*   users = (const int*)d_in[6];
    const int*   items = (const int*)d_in[7];
    float* out = (float*)d_out;

    // ---- workspace layout ----
    // bucketed edges (40 MB) are dead after bucket_to_csr; cur (bf16, 21.8 MB)
    // is aliased on top (build_cur0 runs after pass 4).
    char* p = (char*)d_ws;
    int2* bkt = (int2*)p;                                      // 40 MB
    unsigned short* cur = (unsigned short*)p;                  // 21.76 MB (alias)
    p += (size_t)NNZ * sizeof(int2);
    unsigned short* nxt = (unsigned short*)p;                  // 21.76 MB
    p += (size_t)N_NODES * DIM * sizeof(unsigned short);
    int2* packed = (int2*)p;  p += (size_t)(NNZ + 16) * sizeof(int2); // 40 MB + pad
    int* row_start   = (int*)p;  p += (size_t)(N_NODES + 4) * sizeof(int);
    int* bucket_cnt  = (int*)p;  p += (size_t)(NBUCK + 4) * sizeof(int);
    int* bucket_base = (int*)p;  p += (size_t)(NBUCK + 4) * sizeof(int);
    int* gcursor     = (int*)p;  p += (size_t)(NBUCK + 4) * sizeof(int);
    float* uacc = (float*)p;  p += (size_t)BATCH * DIM * sizeof(float);
    float* iacc = (float*)p;  p += (size_t)BATCH * DIM * sizeof(float);

    // ---- CSR build (bucketed, write-local) ----
    hipMemsetAsync(bucket_cnt, 0, (size_t)NBUCK * sizeof(int), stream);
    hipMemsetAsync(packed + NNZ, 0, 16 * sizeof(int2), stream);   // tail pad
    bucket_hist<<<HBLK, 256, 0, stream>>>(rows, bucket_cnt);
    bucket_scan<<<1, 256, 0, stream>>>(bucket_cnt, bucket_base, gcursor);
    bucket_scatter<<<NBLK, 256, 0, stream>>>(rows, cols, vals, gcursor, bkt);
    bucket_to_csr<<<NBUCK, 512, 0, stream>>>(bucket_base, bkt, row_start, packed);

    // ---- node matrix (aliased over dead bucketed edges) + accumulator init ----
    build_cur0<<<2048, 256, 0, stream>>>(ue, ie, oe, (ushort4*)cur);
    init_acc<<<(BATCH * 16 + 255) / 256, 256, 0, stream>>>(users, items, ue, ie,
                                                           (float4*)uacc, (float4*)iacc);

    // ---- layers 1 and 2: full SpMM, accumulate batch rows ----
    for (int layer = 0; layer < 2; ++layer) {
        spmm_csr8<<<(N_NODES + 3) / 4, 256, 0, stream>>>(row_start,
                                                         (const unsigned long long*)packed,
                                                         cur, nxt);
        gather_add<<<(BATCH * 16 + 255) / 256, 256, 0, stream>>>(users, items, nxt,
                                                                 (float4*)uacc, (float4*)iacc);
        unsigned short* t = cur; cur = nxt; nxt = t;
    }

    // ---- layer 3: only the batch rows ----
    spmm_batch_final8<<<(2 * BATCH + 3) / 4, 256, 0, stream>>>(row_start,
                                                               (const unsigned long long*)packed,
                                                               cur, users, items, uacc, iacc);

    // ---- output ----
    dot_out<<<BATCH / 4, 256, 0, stream>>>(uacc, iacc, out);
}

// Round 6
// 377.126 us; speedup vs baseline: 33.6774x; 1.0598x over previous
//
#include <hip/hip_runtime.h>

#define NUM_USERS 100000
#define NUM_ITEMS 50000
#define NUM_OTHERS 20000
#define N_NODES 170000   // NUM_USERS + NUM_ITEMS + NUM_OTHERS
#define DIM 64
#define NNZ 5000000
#define BATCH 8192

#define BSHIFT 10
#define RPB (1 << BSHIFT)                       // 1024 rows per bucket
#define NBUCK ((N_NODES + RPB - 1) / RPB)       // 167 buckets
#define COLMASK 0x3FFFF                         // 18 bits for col (N_NODES < 2^18)
#define NBLK 512                                // blocks for scatter pass
#define CHUNK ((NNZ + NBLK - 1) / NBLK)         // 9766 edges per block
#define HBLK 1024                               // blocks for hist pass
#define HCHUNK ((NNZ + HBLK - 1) / HBLK)

typedef float f32x2 __attribute__((ext_vector_type(2)));

// fp32 -> bf16 round-to-nearest-even
static __device__ __forceinline__ unsigned f2bf(float f) {
    unsigned u = __float_as_uint(f);
    u = (u + 0x7fff + ((u >> 16) & 1)) >> 16;
    return u;
}
static __device__ __forceinline__ float bflo(unsigned u) {   // low ushort -> f32
    return __uint_as_float(u << 16);
}
static __device__ __forceinline__ float bfhi(unsigned u) {   // high ushort -> f32
    return __uint_as_float(u & 0xFFFF0000u);
}

// ---------------------------------------------------------------------------
// cur0 = concat(user_emb, item_emb, other_emb)  -> bf16
// ---------------------------------------------------------------------------
__global__ void build_cur0(const float* __restrict__ ue,
                           const float* __restrict__ ie,
                           const float* __restrict__ oe,
                           ushort4* __restrict__ cur) {
    const int total = N_NODES * (DIM / 4);
    for (int i = blockIdx.x * blockDim.x + threadIdx.x; i < total;
         i += gridDim.x * blockDim.x) {
        const int node = i >> 4;
        const int sub  = i & 15;
        const float* src;
        if (node < NUM_USERS)                  src = ue + (size_t)node * DIM;
        else if (node < NUM_USERS + NUM_ITEMS) src = ie + (size_t)(node - NUM_USERS) * DIM;
        else                                   src = oe + (size_t)(node - NUM_USERS - NUM_ITEMS) * DIM;
        const float4 f = reinterpret_cast<const float4*>(src)[sub];
        ushort4 o;
        o.x = (unsigned short)f2bf(f.x); o.y = (unsigned short)f2bf(f.y);
        o.z = (unsigned short)f2bf(f.z); o.w = (unsigned short)f2bf(f.w);
        cur[i] = o;
    }
}

// ---------------------------------------------------------------------------
// batch accumulators start as layer-0 embeddings (fp32)
// ---------------------------------------------------------------------------
__global__ void init_acc(const int* __restrict__ users,
                         const int* __restrict__ items,
                         const float* __restrict__ ue,
                         const float* __restrict__ ie,
                         float4* __restrict__ uacc,
                         float4* __restrict__ iacc) {
    const int total = BATCH * (DIM / 4);
    int i = blockIdx.x * blockDim.x + threadIdx.x;
    if (i >= total) return;
    const int b = i >> 4;
    const int sub = i & 15;
    uacc[i] = reinterpret_cast<const float4*>(ue + (size_t)users[b] * DIM)[sub];
    iacc[i] = reinterpret_cast<const float4*>(ie + (size_t)items[b] * DIM)[sub];
}

// ---------------------------------------------------------------------------
// Pass 1: bucket histogram (LDS pre-aggregation)
// ---------------------------------------------------------------------------
__global__ __launch_bounds__(256) void bucket_hist(const int* __restrict__ rows,
                                                   int* __restrict__ bucket_cnt) {
    __shared__ int h[NBUCK];
    for (int i = threadIdx.x; i < NBUCK; i += 256) h[i] = 0;
    __syncthreads();
    const int s = blockIdx.x * HCHUNK;
    const int e = min(s + HCHUNK, NNZ);
    for (int i = s + threadIdx.x; i < e; i += 256)
        atomicAdd(&h[rows[i] >> BSHIFT], 1);
    __syncthreads();
    for (int i = threadIdx.x; i < NBUCK; i += 256)
        if (h[i]) atomicAdd(&bucket_cnt[i], h[i]);
}

// ---------------------------------------------------------------------------
// Pass 2: exclusive scan of 167 bucket counts (one block)
// ---------------------------------------------------------------------------
__global__ __launch_bounds__(256) void bucket_scan(const int* __restrict__ bucket_cnt,
                                                   int* __restrict__ bucket_base,
                                                   int* __restrict__ gcursor) {
    __shared__ int lds[256];
    const int t = threadIdx.x;
    const int v = (t < NBUCK) ? bucket_cnt[t] : 0;
    lds[t] = v;
    __syncthreads();
    int acc = v;
    for (int off = 1; off < 256; off <<= 1) {
        const int add = (t >= off) ? lds[t - off] : 0;
        __syncthreads();
        acc += add;
        lds[t] = acc;
        __syncthreads();
    }
    if (t < NBUCK) {
        const int ex = acc - v;
        bucket_base[t] = ex;
        gcursor[t] = ex;
    }
    if (t == 0) bucket_base[NBUCK] = NNZ;
}

// ---------------------------------------------------------------------------
// Pass 3: scatter edges into bucket-major order; one 8B int2 per edge:
//   .x = (local_row << 18) | col,  .y = val bits
// ---------------------------------------------------------------------------
__global__ __launch_bounds__(256) void bucket_scatter(const int* __restrict__ rows,
                                                      const int* __restrict__ cols,
                                                      const float* __restrict__ vals,
                                                      int* __restrict__ gcursor,
                                                      int2* __restrict__ bkt) {
    __shared__ int h[NBUCK];
    __shared__ int base[NBUCK];
    for (int i = threadIdx.x; i < NBUCK; i += 256) h[i] = 0;
    __syncthreads();
    const int s = blockIdx.x * CHUNK;
    const int e = min(s + CHUNK, NNZ);
    for (int i = s + threadIdx.x; i < e; i += 256)
        atomicAdd(&h[rows[i] >> BSHIFT], 1);
    __syncthreads();
    for (int i = threadIdx.x; i < NBUCK; i += 256)
        base[i] = h[i] ? atomicAdd(&gcursor[i], h[i]) : 0;
    __syncthreads();
    for (int i = threadIdx.x; i < NBUCK; i += 256) h[i] = 0;
    __syncthreads();
    for (int i = s + threadIdx.x; i < e; i += 256) {
        const int r  = rows[i];
        const int bk = r >> BSHIFT;
        const int lr = r & (RPB - 1);
        const int pos = base[bk] + atomicAdd(&h[bk], 1);
        bkt[pos] = make_int2((lr << 18) | cols[i], __float_as_int(vals[i]));
    }
}

// ---------------------------------------------------------------------------
// Pass 4: per-bucket counting sort -> final CSR (packed (col,val)) + rowinfo
//   rowinfo[r] = (abs_start << 8) | len   (len < 256 guaranteed, Poisson(29.4))
// ---------------------------------------------------------------------------
__global__ __launch_bounds__(512) void bucket_to_csr(const int* __restrict__ bucket_base,
                                                     const int2* __restrict__ bkt,
                                                     unsigned* __restrict__ rowinfo,
                                                     int2* __restrict__ packed) {
    __shared__ int cnt[RPB];
    __shared__ int rs[RPB];
    __shared__ int tsum[512];
    const int k = blockIdx.x;
    const int rbase = k << BSHIFT;
    const int bs = bucket_base[k];
    const int be = bucket_base[k + 1];
    const int t = threadIdx.x;

    cnt[t] = 0; cnt[t + 512] = 0;
    __syncthreads();
    for (int i = bs + t; i < be; i += 512)
        atomicAdd(&cnt[bkt[i].x >> 18], 1);
    __syncthreads();

    // exclusive scan of 1024 counts: 2 per thread + Hillis-Steele over totals
    const int v0 = cnt[2 * t];
    const int v1 = cnt[2 * t + 1];
    int acc = v0 + v1;
    tsum[t] = acc;
    __syncthreads();
    for (int off = 1; off < 512; off <<= 1) {
        const int add = (t >= off) ? tsum[t - off] : 0;
        __syncthreads();
        acc += add;
        tsum[t] = acc;
        __syncthreads();
    }
    const int excl = acc - (v0 + v1);
    rs[2 * t]     = excl;
    rs[2 * t + 1] = excl + v0;
    if (rbase + 2 * t < N_NODES)
        rowinfo[rbase + 2 * t]     = ((unsigned)(bs + excl) << 8) | (unsigned)v0;
    if (rbase + 2 * t + 1 < N_NODES)
        rowinfo[rbase + 2 * t + 1] = ((unsigned)(bs + excl + v0) << 8) | (unsigned)v1;
    __syncthreads();

    // scatter; atomicAdd on rs yields sequential positions within each row
    for (int i = bs + t; i < be; i += 512) {
        const int2 pk = bkt[i];
        const int lr = pk.x >> 18;
        const int pos = bs + atomicAdd(&rs[lr], 1);
        packed[pos] = make_int2(pk.x & COLMASK, pk.y);
    }
}

// ---------------------------------------------------------------------------
// SpMM gather core: 32 edge-slots per iteration, 8 lanes per edge (16B/lane),
// masked tail slots clamped to col 0 (L1-resident, ~free). f32x2 packed FMA.
// ---------------------------------------------------------------------------
static __device__ __forceinline__ void spmm_row_accum(
        const unsigned long long* __restrict__ packed,
        const unsigned short* __restrict__ x,
        int s, int e, int g, int d8,
        f32x2& a0, f32x2& a1, f32x2& a2, f32x2& a3) {
    for (int i = s; i < e; i += 32) {
        const int j0 = i + g;
        const int j1 = j0 + 8;
        const int j2 = j0 + 16;
        const int j3 = j0 + 24;
        const unsigned long long p0 = __builtin_nontemporal_load(packed + j0);
        const unsigned long long p1 = __builtin_nontemporal_load(packed + j1);
        const unsigned long long p2 = __builtin_nontemporal_load(packed + j2);
        const unsigned long long p3 = __builtin_nontemporal_load(packed + j3);
        const int   c0 = (j0 < e) ? (int)(p0 & 0xFFFFFFFFu) : 0;
        const int   c1 = (j1 < e) ? (int)(p1 & 0xFFFFFFFFu) : 0;
        const int   c2 = (j2 < e) ? (int)(p2 & 0xFFFFFFFFu) : 0;
        const int   c3 = (j3 < e) ? (int)(p3 & 0xFFFFFFFFu) : 0;
        const float v0 = (j0 < e) ? __uint_as_float((unsigned)(p0 >> 32)) : 0.f;
        const float v1 = (j1 < e) ? __uint_as_float((unsigned)(p1 >> 32)) : 0.f;
        const float v2 = (j2 < e) ? __uint_as_float((unsigned)(p2 >> 32)) : 0.f;
        const float v3 = (j3 < e) ? __uint_as_float((unsigned)(p3 >> 32)) : 0.f;
        const uint4 x0 = *reinterpret_cast<const uint4*>(x + c0 * DIM + d8);
        const uint4 x1 = *reinterpret_cast<const uint4*>(x + c1 * DIM + d8);
        const uint4 x2 = *reinterpret_cast<const uint4*>(x + c2 * DIM + d8);
        const uint4 x3 = *reinterpret_cast<const uint4*>(x + c3 * DIM + d8);
        const f32x2 w0 = {v0, v0}, w1 = {v1, v1}, w2 = {v2, v2}, w3 = {v3, v3};
        a0 += w0 * (f32x2){bflo(x0.x), bfhi(x0.x)};
        a1 += w0 * (f32x2){bflo(x0.y), bfhi(x0.y)};
        a2 += w0 * (f32x2){bflo(x0.z), bfhi(x0.z)};
        a3 += w0 * (f32x2){bflo(x0.w), bfhi(x0.w)};
        a0 += w1 * (f32x2){bflo(x1.x), bfhi(x1.x)};
        a1 += w1 * (f32x2){bflo(x1.y), bfhi(x1.y)};
        a2 += w1 * (f32x2){bflo(x1.z), bfhi(x1.z)};
        a3 += w1 * (f32x2){bflo(x1.w), bfhi(x1.w)};
        a0 += w2 * (f32x2){bflo(x2.x), bfhi(x2.x)};
        a1 += w2 * (f32x2){bflo(x2.y), bfhi(x2.y)};
        a2 += w2 * (f32x2){bflo(x2.z), bfhi(x2.z)};
        a3 += w2 * (f32x2){bflo(x2.w), bfhi(x2.w)};
        a0 += w3 * (f32x2){bflo(x3.x), bfhi(x3.x)};
        a1 += w3 * (f32x2){bflo(x3.y), bfhi(x3.y)};
        a2 += w3 * (f32x2){bflo(x3.z), bfhi(x3.z)};
        a3 += w3 * (f32x2){bflo(x3.w), bfhi(x3.w)};
    }
}

static __device__ __forceinline__ void butterfly8(f32x2& a0, f32x2& a1,
                                                  f32x2& a2, f32x2& a3) {
    #pragma unroll
    for (int off = 8; off < 64; off <<= 1) {
        a0.x += __shfl_xor(a0.x, off); a0.y += __shfl_xor(a0.y, off);
        a1.x += __shfl_xor(a1.x, off); a1.y += __shfl_xor(a1.y, off);
        a2.x += __shfl_xor(a2.x, off); a2.y += __shfl_xor(a2.y, off);
        a3.x += __shfl_xor(a3.x, off); a3.y += __shfl_xor(a3.y, off);
    }
}

// ---------------------------------------------------------------------------
// Full SpMM: one wave per row
// ---------------------------------------------------------------------------
__global__ __launch_bounds__(256) void spmm_csr8(const unsigned* __restrict__ rowinfo,
                                                 const unsigned long long* __restrict__ packed,
                                                 const unsigned short* __restrict__ x,
                                                 unsigned short* __restrict__ y) {
    const int row  = blockIdx.x * 4 + (threadIdx.x >> 6);
    const int lane = threadIdx.x & 63;
    if (row >= N_NODES) return;
    const unsigned info = rowinfo[row];
    const int s = (int)(info >> 8);
    const int e = s + (int)(info & 0xFFu);
    const int g  = lane >> 3;          // edge group 0..7
    const int d8 = (lane & 7) * 8;     // dim base 0..56

    f32x2 a0 = {0, 0}, a1 = {0, 0}, a2 = {0, 0}, a3 = {0, 0};
    spmm_row_accum(packed, x, s, e, g, d8, a0, a1, a2, a3);
    butterfly8(a0, a1, a2, a3);

    if (lane < 8) {
        uint4 o;
        o.x = f2bf(a0.x) | (f2bf(a0.y) << 16);
        o.y = f2bf(a1.x) | (f2bf(a1.y) << 16);
        o.z = f2bf(a2.x) | (f2bf(a2.y) << 16);
        o.w = f2bf(a3.x) | (f2bf(a3.y) << 16);
        *reinterpret_cast<uint4*>(y + row * DIM + lane * 8) = o;
    }
}

// ---------------------------------------------------------------------------
// Layer-3: only batch rows, accumulate into fp32 uacc/iacc
// ---------------------------------------------------------------------------
__global__ __launch_bounds__(256) void spmm_batch_final8(const unsigned* __restrict__ rowinfo,
                                                         const unsigned long long* __restrict__ packed,
                                                         const unsigned short* __restrict__ x,
                                                         const int* __restrict__ users,
                                                         const int* __restrict__ items,
                                                         float* __restrict__ uacc,
                                                         float* __restrict__ iacc) {
    const int w    = blockIdx.x * 4 + (threadIdx.x >> 6);   // [0, 2*BATCH)
    const int lane = threadIdx.x & 63;
    if (w >= 2 * BATCH) return;
    const int b = w >> 1;
    const int isItem = w & 1;
    const int row = isItem ? (NUM_USERS + items[b]) : users[b];
    const unsigned info = rowinfo[row];
    const int s = (int)(info >> 8);
    const int e = s + (int)(info & 0xFFu);
    const int g  = lane >> 3;
    const int d8 = (lane & 7) * 8;

    f32x2 a0 = {0, 0}, a1 = {0, 0}, a2 = {0, 0}, a3 = {0, 0};
    spmm_row_accum(packed, x, s, e, g, d8, a0, a1, a2, a3);
    butterfly8(a0, a1, a2, a3);

    if (lane < 8) {
        float* dst = (isItem ? iacc : uacc) + (size_t)b * DIM + lane * 8;
        float4 q0 = reinterpret_cast<float4*>(dst)[0];
        float4 q1 = reinterpret_cast<float4*>(dst)[1];
        q0.x += a0.x; q0.y += a0.y; q0.z += a1.x; q0.w += a1.y;
        q1.x += a2.x; q1.y += a2.y; q1.z += a3.x; q1.w += a3.y;
        reinterpret_cast<float4*>(dst)[0] = q0;
        reinterpret_cast<float4*>(dst)[1] = q1;
    }
}

// ---------------------------------------------------------------------------
// uacc/iacc += y (bf16) at the batch rows (layers 1 and 2)
// ---------------------------------------------------------------------------
__global__ void gather_add(const int* __restrict__ users,
                           const int* __restrict__ items,
                           const unsigned short* __restrict__ y,
                           float4* __restrict__ uacc,
                           float4* __restrict__ iacc) {
    const int total = BATCH * (DIM / 4);
    int i = blockIdx.x * blockDim.x + threadIdx.x;
    if (i >= total) return;
    const int b = i >> 4;
    const int sub = i & 15;
    const int un = users[b];
    const int in = NUM_USERS + items[b];
    float4 a = uacc[i];
    const ushort4 yu = *reinterpret_cast<const ushort4*>(y + (size_t)un * DIM + sub * 4);
    a.x += bflo(yu.x); a.y += bflo(yu.y); a.z += bflo(yu.z); a.w += bflo(yu.w);
    uacc[i] = a;
    float4 c = iacc[i];
    const ushort4 yi = *reinterpret_cast<const ushort4*>(y + (size_t)in * DIM + sub * 4);
    c.x += bflo(yi.x); c.y += bflo(yi.y); c.z += bflo(yi.z); c.w += bflo(yi.w);
    iacc[i] = c;
}

// ---------------------------------------------------------------------------
// gamma[b] = dot(uacc[b], iacc[b]) / 16
// ---------------------------------------------------------------------------
__global__ void dot_out(const float* __restrict__ uacc,
                        const float* __restrict__ iacc,
                        float* __restrict__ gamma) {
    const int b = blockIdx.x * (blockDim.x / 64) + (threadIdx.x / 64);
    const int lane = threadIdx.x & 63;
    if (b >= BATCH) return;
    float p = uacc[b * DIM + lane] * iacc[b * DIM + lane];
    #pragma unroll
    for (int off = 32; off > 0; off >>= 1) p += __shfl_down(p, off);
    if (lane == 0) gamma[b] = p * 0.0625f;
}

// ---------------------------------------------------------------------------
extern "C" void kernel_launch(void* const* d_in, const int* in_sizes, int n_in,
                              void* d_out, int out_size, void* d_ws, size_t ws_size,
                              hipStream_t stream) {
    const float* ue    = (const float*)d_in[0];
    const float* ie    = (const float*)d_in[1];
    const float* oe    = (const float*)d_in[2];
    const float* vals  = (const float*)d_in[3];
    const int*   rows  = (const int*)d_in[4];
    const int*   cols  = (const int*)d_in[5];
    const int*   users = (const int*)d_in[6];
    const int*   items = (const int*)d_in[7];
    float* out = (float*)d_out;

    // ---- workspace layout ----
    // bucketed edges (40 MB) are dead after bucket_to_csr; cur (bf16, 21.8 MB)
    // is aliased on top (build_cur0 runs after pass 4).
    char* p = (char*)d_ws;
    int2* bkt = (int2*)p;                                      // 40 MB
    unsigned short* cur = (unsigned short*)p;                  // 21.76 MB (alias)
    p += (size_t)NNZ * sizeof(int2);
    unsigned short* nxt = (unsigned short*)p;                  // 21.76 MB
    p += (size_t)N_NODES * DIM * sizeof(unsigned short);
    int2* packed = (int2*)p;  p += (size_t)(NNZ + 32) * sizeof(int2); // 40 MB + pad
    unsigned* rowinfo = (unsigned*)p;  p += (size_t)(N_NODES + 4) * sizeof(unsigned);
    int* bucket_cnt  = (int*)p;  p += (size_t)(NBUCK + 4) * sizeof(int);
    int* bucket_base = (int*)p;  p += (size_t)(NBUCK + 4) * sizeof(int);
    int* gcursor     = (int*)p;  p += (size_t)(NBUCK + 4) * sizeof(int);
    float* uacc = (float*)p;  p += (size_t)BATCH * DIM * sizeof(float);
    float* iacc = (float*)p;  p += (size_t)BATCH * DIM * sizeof(float);

    // ---- CSR build (bucketed, write-local) ----
    hipMemsetAsync(bucket_cnt, 0, (size_t)NBUCK * sizeof(int), stream);
    bucket_hist<<<HBLK, 256, 0, stream>>>(rows, bucket_cnt);
    bucket_scan<<<1, 256, 0, stream>>>(bucket_cnt, bucket_base, gcursor);
    bucket_scatter<<<NBLK, 256, 0, stream>>>(rows, cols, vals, gcursor, bkt);
    bucket_to_csr<<<NBUCK, 512, 0, stream>>>(bucket_base, bkt, rowinfo, packed);

    // ---- node matrix (aliased over dead bucketed edges) + accumulator init ----
    build_cur0<<<2048, 256, 0, stream>>>(ue, ie, oe, (ushort4*)cur);
    init_acc<<<(BATCH * 16 + 255) / 256, 256, 0, stream>>>(users, items, ue, ie,
                                                           (float4*)uacc, (float4*)iacc);

    // ---- layers 1 and 2: full SpMM, accumulate batch rows ----
    for (int layer = 0; layer < 2; ++layer) {
        spmm_csr8<<<(N_NODES + 3) / 4, 256, 0, stream>>>(rowinfo,
                                                         (const unsigned long long*)packed,
                                                         cur, nxt);
        gather_add<<<(BATCH * 16 + 255) / 256, 256, 0, stream>>>(users, items, nxt,
                                                                 (float4*)uacc, (float4*)iacc);
        unsigned short* t = cur; cur = nxt; nxt = t;
    }

    // ---- layer 3: only the batch rows ----
    spmm_batch_final8<<<(2 * BATCH + 3) / 4, 256, 0, stream>>>(rowinfo,
                                                               (const unsigned long long*)packed,
                                                               cur, users, items, uacc, iacc);

    // ---- output ----
    dot_out<<<BATCH / 4, 256, 0, stream>>>(uacc, iacc, out);
}